// Round 1
// baseline (2641.724 us; speedup 1.0000x reference)
//
#include <hip/hip_runtime.h>

#define NN 50000
#define NE 800000
#define NG 512

// ---------- degree / norm ----------
__global__ void deg_init_k(float* __restrict__ deg, int n) {
    int i = blockIdx.x * blockDim.x + threadIdx.x;
    if (i < n) deg[i] = 1.0f;  // self-loop
}

__global__ void deg_count_k(const int* __restrict__ dst, float* __restrict__ deg, int e) {
    int i = blockIdx.x * blockDim.x + threadIdx.x;
    if (i < e) atomicAdd(&deg[dst[i]], 1.0f);
}

__global__ void rsqrt_k(float* __restrict__ deg, int n) {
    int i = blockIdx.x * blockDim.x + threadIdx.x;
    if (i < n) deg[i] = rsqrtf(deg[i]);  // deg >= 1 always
}

// ---------- layer 1: A[n,f] = dinv[n] * sum_k x[n,k] * W1[k,f], Fin=3, Fout=32 ----------
__global__ void mm1_k(const float* __restrict__ x, const float* __restrict__ W1,
                      const float* __restrict__ dinv, float* __restrict__ A, int n) {
    int idx = blockIdx.x * blockDim.x + threadIdx.x;
    if (idx >= n * 32) return;
    int node = idx >> 5, f = idx & 31;
    const float* xr = x + node * 3;
    float v = xr[0] * W1[f] + xr[1] * W1[32 + f] + xr[2] * W1[64 + f];
    A[idx] = v * dinv[node];
}

// ---------- edge scatter: B[dst,:] += A[src,:]  (float4 gather, scalar atomics) ----------
template <int F>
__global__ void scatter_k(const int* __restrict__ src, const int* __restrict__ dst,
                          const float* __restrict__ A, float* __restrict__ B, int e) {
    constexpr int FV = F / 4;
    int id = blockIdx.x * blockDim.x + threadIdx.x;
    if (id >= e * FV) return;
    int ed = id / FV;
    int j = (id - ed * FV) * 4;
    int s = src[ed], d = dst[ed];
    float4 v = *(const float4*)(A + (size_t)s * F + j);
    float* bp = B + (size_t)d * F + j;
    atomicAdd(bp + 0, v.x);
    atomicAdd(bp + 1, v.y);
    atomicAdd(bp + 2, v.z);
    atomicAdd(bp + 3, v.w);
}

// ---------- fused finalize + matmul + pre-scale ----------
// A[n,f] = dinv[n] * sum_k relu(dinv[n]*B[n,k] + bias[k]) * W[k,f]
template <int Fin, int Fout, int NB>  // NB*Fout == 256
__global__ __launch_bounds__(256) void mmfused_k(
    const float* __restrict__ B, const float* __restrict__ W,
    const float* __restrict__ bias, const float* __restrict__ dinv,
    float* __restrict__ A, int n) {
    __shared__ float act[NB * Fin];
    int t = threadIdx.x;
    int node0 = blockIdx.x * NB;
    for (int i = t; i < NB * Fin; i += 256) {
        int nl = i / Fin, k = i - nl * Fin;
        int node = node0 + nl;
        float v = 0.0f;
        if (node < n) v = fmaxf(fmaf(dinv[node], B[(size_t)node * Fin + k], bias[k]), 0.0f);
        act[i] = v;
    }
    __syncthreads();
    int nl = t / Fout, f = t - nl * Fout;
    int node = node0 + nl;
    if (node < n) {
        float acc = 0.0f;
#pragma unroll
        for (int k = 0; k < Fin; ++k)
            acc = fmaf(act[nl * Fin + k], W[k * Fout + f], acc);
        A[(size_t)node * Fout + f] = acc * dinv[node];
    }
}

// ---------- pooling: pooled[g,k] += relu(dinv[n]*B[n,k] + b3[k]) ----------
__global__ void pool_k(const float* __restrict__ B, const float* __restrict__ dinv,
                       const float* __restrict__ b3, const int* __restrict__ batch,
                       float* __restrict__ pooled, int n) {
    int idx = blockIdx.x * blockDim.x + threadIdx.x;
    if (idx >= n * 128) return;
    int node = idx >> 7, k = idx & 127;
    float v = fmaxf(fmaf(dinv[node], B[idx], b3[k]), 0.0f);
    atomicAdd(&pooled[batch[node] * 128 + k], v);
}

__global__ void cnt_k(const int* __restrict__ batch, float* __restrict__ cnt, int n) {
    int i = blockIdx.x * blockDim.x + threadIdx.x;
    if (i < n) atomicAdd(&cnt[batch[i]], 1.0f);
}

// ---------- head: out[g,:] = relu(mean_pool @ Wf1 + bf1) @ Wf2 + bf2 ----------
__global__ __launch_bounds__(64) void head_k(
    const float* __restrict__ pooled, const float* __restrict__ cnt,
    const float* __restrict__ Wf1, const float* __restrict__ bf1,
    const float* __restrict__ Wf2, const float* __restrict__ bf2,
    float* __restrict__ out) {
    __shared__ float pm[128];
    __shared__ float z[32];
    int g = blockIdx.x, t = threadIdx.x;
    float c = fmaxf(cnt[g], 1.0f);
    pm[t] = pooled[g * 128 + t] / c;
    pm[t + 64] = pooled[g * 128 + 64 + t] / c;
    __syncthreads();
    if (t < 32) {
        float acc = bf1[t];
#pragma unroll 4
        for (int k = 0; k < 128; ++k) acc = fmaf(pm[k], Wf1[k * 32 + t], acc);
        z[t] = fmaxf(acc, 0.0f);
    }
    __syncthreads();
    if (t < 4) {
        float acc = bf2[t];
#pragma unroll
        for (int j = 0; j < 32; ++j) acc = fmaf(z[j], Wf2[j * 4 + t], acc);
        out[g * 4 + t] = acc;
    }
}

extern "C" void kernel_launch(void* const* d_in, const int* in_sizes, int n_in,
                              void* d_out, int out_size, void* d_ws, size_t ws_size,
                              hipStream_t stream) {
    const float* x   = (const float*)d_in[0];
    const int*  ei   = (const int*)d_in[1];
    const int*  batch= (const int*)d_in[2];
    const float* W1  = (const float*)d_in[3];
    const float* b1  = (const float*)d_in[4];
    const float* W2  = (const float*)d_in[5];
    const float* b2  = (const float*)d_in[6];
    const float* W3  = (const float*)d_in[7];
    const float* b3  = (const float*)d_in[8];
    const float* Wf1 = (const float*)d_in[9];
    const float* bf1 = (const float*)d_in[10];
    const float* Wf2 = (const float*)d_in[11];
    const float* bf2 = (const float*)d_in[12];
    float* out = (float*)d_out;

    float* A      = (float*)d_ws;          // N*128
    float* B      = A + (size_t)NN * 128;  // N*128
    float* dinv   = B + (size_t)NN * 128;  // N
    float* pooled = dinv + NN;             // 512*128
    float* cnt    = pooled + NG * 128;     // 512

    const int* src = ei;
    const int* dst = ei + NE;

    // norm
    deg_init_k<<<(NN + 255) / 256, 256, 0, stream>>>(dinv, NN);
    deg_count_k<<<(NE + 255) / 256, 256, 0, stream>>>(dst, dinv, NE);
    rsqrt_k<<<(NN + 255) / 256, 256, 0, stream>>>(dinv, NN);

    // layer 1 (3 -> 32)
    mm1_k<<<(NN * 32 + 255) / 256, 256, 0, stream>>>(x, W1, dinv, A, NN);
    hipMemcpyAsync(B, A, (size_t)NN * 32 * 4, hipMemcpyDeviceToDevice, stream);
    scatter_k<32><<<(NE * 8 + 255) / 256, 256, 0, stream>>>(src, dst, A, B, NE);

    // layer 2 (32 -> 64)
    mmfused_k<32, 64, 4><<<(NN + 3) / 4, 256, 0, stream>>>(B, W2, b2, dinv, A, NN);
    hipMemcpyAsync(B, A, (size_t)NN * 64 * 4, hipMemcpyDeviceToDevice, stream);
    scatter_k<64><<<(NE * 16 + 255) / 256, 256, 0, stream>>>(src, dst, A, B, NE);

    // layer 3 (64 -> 128)
    mmfused_k<64, 128, 2><<<(NN + 1) / 2, 256, 0, stream>>>(B, W3, b3, dinv, A, NN);
    hipMemcpyAsync(B, A, (size_t)NN * 128 * 4, hipMemcpyDeviceToDevice, stream);
    scatter_k<128><<<(NE * 32 + 255) / 256, 256, 0, stream>>>(src, dst, A, B, NE);

    // pooling + head
    hipMemsetAsync(pooled, 0, (size_t)(NG * 128 + NG) * 4, stream);
    pool_k<<<(NN * 128 + 255) / 256, 256, 0, stream>>>(B, dinv, b3, batch, pooled, NN);
    cnt_k<<<(NN + 255) / 256, 256, 0, stream>>>(batch, cnt, NN);
    head_k<<<NG, 64, 0, stream>>>(pooled, cnt, Wf1, bf1, Wf2, bf2, out);
}

// Round 2
// 434.808 us; speedup vs baseline: 6.0756x; 6.0756x over previous
//
#include <hip/hip_runtime.h>

#define NN 50000
#define NE 800000
#define NG 512

// ---------- histogram of dst (in-degree) ----------
__global__ void hist_k(const int* __restrict__ dst, int* __restrict__ cnt, int e) {
    int i = blockIdx.x * blockDim.x + threadIdx.x;
    if (i < e) atomicAdd(&cnt[dst[i]], 1);
}

__global__ void dinv_k(const int* __restrict__ cnt, float* __restrict__ dinv, int n) {
    int i = blockIdx.x * blockDim.x + threadIdx.x;
    if (i < n) dinv[i] = rsqrtf((float)(cnt[i] + 1));  // +1 self-loop
}

// ---------- 3-kernel exclusive prefix scan over cnt -> rowptr ----------
#define SCAN_B 256
__global__ __launch_bounds__(SCAN_B) void scan1_k(const int* __restrict__ cnt,
                                                  int* __restrict__ excl,
                                                  int* __restrict__ bsum, int n) {
    __shared__ int sh[SCAN_B];
    int t = threadIdx.x, i = blockIdx.x * SCAN_B + t;
    int v = (i < n) ? cnt[i] : 0;
    sh[t] = v;
    __syncthreads();
    for (int off = 1; off < SCAN_B; off <<= 1) {
        int x = (t >= off) ? sh[t - off] : 0;
        __syncthreads();
        sh[t] += x;
        __syncthreads();
    }
    if (i < n) excl[i] = sh[t] - v;  // block-local exclusive
    if (t == SCAN_B - 1) bsum[blockIdx.x] = sh[t];
}

__global__ __launch_bounds__(SCAN_B) void scan2_k(int* __restrict__ bsum, int nb) {
    __shared__ int sh[SCAN_B];
    int t = threadIdx.x;
    int v = (t < nb) ? bsum[t] : 0;
    sh[t] = v;
    __syncthreads();
    for (int off = 1; off < SCAN_B; off <<= 1) {
        int x = (t >= off) ? sh[t - off] : 0;
        __syncthreads();
        sh[t] += x;
        __syncthreads();
    }
    if (t < nb) bsum[t] = sh[t] - v;  // exclusive block offsets
}

__global__ __launch_bounds__(SCAN_B) void scan3_k(int* __restrict__ excl,
                                                  const int* __restrict__ bsum,
                                                  int n, int e) {
    int i = blockIdx.x * SCAN_B + threadIdx.x;
    if (i < n) excl[i] += bsum[blockIdx.x];
    if (i == 0) excl[n] = e;
}

// ---------- fill CSR buckets: eidx sorted by dst, values = src ----------
__global__ void bucket_k(const int* __restrict__ src, const int* __restrict__ dst,
                         const int* __restrict__ rowptr, int* __restrict__ fill,
                         int* __restrict__ eidx, int e) {
    int i = blockIdx.x * blockDim.x + threadIdx.x;
    if (i >= e) return;
    int d = dst[i];
    int pos = rowptr[d] + atomicAdd(&fill[d], 1);
    eidx[pos] = src[i];
}

// ---------- layer 1: A[n,f] = dinv[n] * (x @ W1), Fin=3, Fout=32 ----------
__global__ void mm1_k(const float* __restrict__ x, const float* __restrict__ W1,
                      const float* __restrict__ dinv, float* __restrict__ A, int n) {
    int idx = blockIdx.x * blockDim.x + threadIdx.x;
    if (idx >= n * 32) return;
    int node = idx >> 5, f = idx & 31;
    const float* xr = x + node * 3;
    float v = xr[0] * W1[f] + xr[1] * W1[32 + f] + xr[2] * W1[64 + f];
    A[idx] = v * dinv[node];
}

// ---------- gather aggregation: B[d,:] = A[d,:] + sum_{e in CSR[d]} A[eidx[e],:] ----------
template <int F>
__global__ __launch_bounds__(256) void gather_k(const int* __restrict__ rowptr,
                                                const int* __restrict__ eidx,
                                                const float* __restrict__ A,
                                                float* __restrict__ B, int n) {
    constexpr int G = 256 / F;
    int t = threadIdx.x;
    int node = blockIdx.x * G + t / F;
    int f = t % F;
    if (node >= n) return;
    int e0 = rowptr[node], e1 = rowptr[node + 1];
    float acc = A[(size_t)node * F + f];  // self-loop
    int e = e0;
    for (; e + 1 < e1; e += 2) {  // unroll x2 for load ILP
        int s0 = eidx[e], s1 = eidx[e + 1];
        float v0 = A[(size_t)s0 * F + f];
        float v1 = A[(size_t)s1 * F + f];
        acc += v0;
        acc += v1;
    }
    if (e < e1) acc += A[(size_t)eidx[e] * F + f];
    B[(size_t)node * F + f] = acc;
}

// ---------- fused finalize + matmul + pre-scale ----------
// A[n,f] = dinv[n] * sum_k relu(dinv[n]*B[n,k] + bias[k]) * W[k,f]
template <int Fin, int Fout, int NB>  // NB*Fout == 256
__global__ __launch_bounds__(256) void mmfused_k(
    const float* __restrict__ B, const float* __restrict__ W,
    const float* __restrict__ bias, const float* __restrict__ dinv,
    float* __restrict__ A, int n) {
    __shared__ float act[NB * Fin];
    int t = threadIdx.x;
    int node0 = blockIdx.x * NB;
    for (int i = t; i < NB * Fin; i += 256) {
        int nl = i / Fin, k = i - nl * Fin;
        int node = node0 + nl;
        float v = 0.0f;
        if (node < n) v = fmaxf(fmaf(dinv[node], B[(size_t)node * Fin + k], bias[k]), 0.0f);
        act[i] = v;
    }
    __syncthreads();
    int nl = t / Fout, f = t - nl * Fout;
    int node = node0 + nl;
    if (node < n) {
        float acc = 0.0f;
#pragma unroll
        for (int k = 0; k < Fin; ++k)
            acc = fmaf(act[nl * Fin + k], W[k * Fout + f], acc);
        A[(size_t)node * Fout + f] = acc * dinv[node];
    }
}

// ---------- segmented mean-pool (batch is sorted) ----------
#define NPB 32  // nodes per block
__global__ __launch_bounds__(128) void pool2_k(
    const float* __restrict__ B, const float* __restrict__ dinv,
    const float* __restrict__ b3, const int* __restrict__ batch,
    float* __restrict__ pooled, float* __restrict__ cntg, int n) {
    int f = threadIdx.x;
    int n0 = blockIdx.x * NPB;
    if (n0 >= n) return;
    int n1 = min(n0 + NPB, n);
    float acc = 0.0f, cct = 0.0f;
    int cur = batch[n0];
    for (int node = n0; node < n1; ++node) {
        int g = batch[node];
        if (g != cur) {
            atomicAdd(&pooled[cur * 128 + f], acc);
            if (f == 0) atomicAdd(&cntg[cur], cct);
            acc = 0.0f;
            cct = 0.0f;
            cur = g;
        }
        acc += fmaxf(fmaf(dinv[node], B[(size_t)node * 128 + f], b3[f]), 0.0f);
        cct += 1.0f;
    }
    atomicAdd(&pooled[cur * 128 + f], acc);
    if (f == 0) atomicAdd(&cntg[cur], cct);
}

// ---------- head: out[g,:] = relu(mean_pool @ Wf1 + bf1) @ Wf2 + bf2 ----------
__global__ __launch_bounds__(64) void head_k(
    const float* __restrict__ pooled, const float* __restrict__ cnt,
    const float* __restrict__ Wf1, const float* __restrict__ bf1,
    const float* __restrict__ Wf2, const float* __restrict__ bf2,
    float* __restrict__ out) {
    __shared__ float pm[128];
    __shared__ float z[32];
    int g = blockIdx.x, t = threadIdx.x;
    float c = fmaxf(cnt[g], 1.0f);
    pm[t] = pooled[g * 128 + t] / c;
    pm[t + 64] = pooled[g * 128 + 64 + t] / c;
    __syncthreads();
    if (t < 32) {
        float acc = bf1[t];
#pragma unroll 4
        for (int k = 0; k < 128; ++k) acc = fmaf(pm[k], Wf1[k * 32 + t], acc);
        z[t] = fmaxf(acc, 0.0f);
    }
    __syncthreads();
    if (t < 4) {
        float acc = bf2[t];
#pragma unroll
        for (int j = 0; j < 32; ++j) acc = fmaf(z[j], Wf2[j * 4 + t], acc);
        out[g * 4 + t] = acc;
    }
}

extern "C" void kernel_launch(void* const* d_in, const int* in_sizes, int n_in,
                              void* d_out, int out_size, void* d_ws, size_t ws_size,
                              hipStream_t stream) {
    const float* x    = (const float*)d_in[0];
    const int*   ei   = (const int*)d_in[1];
    const int*   batch= (const int*)d_in[2];
    const float* W1   = (const float*)d_in[3];
    const float* b1   = (const float*)d_in[4];
    const float* W2   = (const float*)d_in[5];
    const float* b2   = (const float*)d_in[6];
    const float* W3   = (const float*)d_in[7];
    const float* b3   = (const float*)d_in[8];
    const float* Wf1  = (const float*)d_in[9];
    const float* bf1  = (const float*)d_in[10];
    const float* Wf2  = (const float*)d_in[11];
    const float* bf2  = (const float*)d_in[12];
    float* out = (float*)d_out;

    // workspace layout (all 4-byte elems)
    float* A      = (float*)d_ws;              // N*128
    float* B      = A + (size_t)NN * 128;      // N*128
    float* dinv   = B + (size_t)NN * 128;      // N
    float* pooled = dinv + NN;                 // NG*128   } contiguous memset
    float* cntg   = pooled + NG * 128;         // NG       }
    int* cnt      = (int*)(cntg + NG);         // N        } contiguous memset
    int* fill     = cnt + NN;                  // N        }
    int* rowptr   = fill + NN;                 // N+1
    int* bsum     = rowptr + NN + 1;           // 256
    int* eidx     = bsum + 256;                // E

    const int* src = ei;
    const int* dst = ei + NE;

    const int NB_SCAN = (NN + SCAN_B - 1) / SCAN_B;  // 196

    // ---- build CSR (dst-sorted) + norms ----
    hipMemsetAsync(cnt, 0, (size_t)2 * NN * 4, stream);                 // cnt + fill
    hipMemsetAsync(pooled, 0, (size_t)(NG * 128 + NG) * 4, stream);     // pooled + cntg
    hist_k<<<(NE + 255) / 256, 256, 0, stream>>>(dst, cnt, NE);
    dinv_k<<<(NN + 255) / 256, 256, 0, stream>>>(cnt, dinv, NN);
    scan1_k<<<NB_SCAN, SCAN_B, 0, stream>>>(cnt, rowptr, bsum, NN);
    scan2_k<<<1, SCAN_B, 0, stream>>>(bsum, NB_SCAN);
    scan3_k<<<NB_SCAN, SCAN_B, 0, stream>>>(rowptr, bsum, NN, NE);
    bucket_k<<<(NE + 255) / 256, 256, 0, stream>>>(src, dst, rowptr, fill, eidx, NE);

    // ---- layer 1 (3 -> 32) ----
    mm1_k<<<(NN * 32 + 255) / 256, 256, 0, stream>>>(x, W1, dinv, A, NN);
    gather_k<32><<<(NN * 32 + 255) / 256, 256, 0, stream>>>(rowptr, eidx, A, B, NN);

    // ---- layer 2 (32 -> 64) ----
    mmfused_k<32, 64, 4><<<(NN + 3) / 4, 256, 0, stream>>>(B, W2, b1, dinv, A, NN);
    gather_k<64><<<(NN * 64 + 255) / 256, 256, 0, stream>>>(rowptr, eidx, A, B, NN);

    // ---- layer 3 (64 -> 128) ----
    mmfused_k<64, 128, 2><<<(NN + 1) / 2, 256, 0, stream>>>(B, W3, b2, dinv, A, NN);
    gather_k<128><<<(NN * 128 + 255) / 256, 256, 0, stream>>>(rowptr, eidx, A, B, NN);

    // ---- pool + head ----
    pool2_k<<<(NN + NPB - 1) / NPB, 128, 0, stream>>>(B, dinv, b3, batch, pooled, cntg, NN);
    head_k<<<NG, 64, 0, stream>>>(pooled, cntg, Wf1, bf1, Wf2, bf2, out);
}

// Round 3
// 322.049 us; speedup vs baseline: 8.2029x; 1.3501x over previous
//
#include <hip/hip_runtime.h>

#define NN 50000
#define NE 800000
#define NG 512

// ---------- histogram of dst (in-degree) ----------
__global__ void hist_k(const int* __restrict__ dst, int* __restrict__ cnt, int e) {
    int i = blockIdx.x * blockDim.x + threadIdx.x;
    if (i < e) atomicAdd(&cnt[dst[i]], 1);
}

// ---------- dinv = rsqrt(deg), xs[n,4] = dinv[n]*x[n,0:3] (padded) ----------
__global__ void dinvxs_k(const int* __restrict__ cnt, const float* __restrict__ x,
                         float* __restrict__ dinv, float* __restrict__ xs, int n) {
    int i = blockIdx.x * blockDim.x + threadIdx.x;
    if (i >= n) return;
    float d = rsqrtf((float)(cnt[i] + 1));  // +1 self-loop
    dinv[i] = d;
    float4 v;
    v.x = x[i * 3 + 0] * d;
    v.y = x[i * 3 + 1] * d;
    v.z = x[i * 3 + 2] * d;
    v.w = 0.0f;
    *(float4*)(xs + (size_t)i * 4) = v;
}

// ---------- 3-kernel exclusive prefix scan over cnt -> rowptr ----------
#define SCAN_B 256
__global__ __launch_bounds__(SCAN_B) void scan1_k(const int* __restrict__ cnt,
                                                  int* __restrict__ excl,
                                                  int* __restrict__ bsum, int n) {
    __shared__ int sh[SCAN_B];
    int t = threadIdx.x, i = blockIdx.x * SCAN_B + t;
    int v = (i < n) ? cnt[i] : 0;
    sh[t] = v;
    __syncthreads();
    for (int off = 1; off < SCAN_B; off <<= 1) {
        int x = (t >= off) ? sh[t - off] : 0;
        __syncthreads();
        sh[t] += x;
        __syncthreads();
    }
    if (i < n) excl[i] = sh[t] - v;
    if (t == SCAN_B - 1) bsum[blockIdx.x] = sh[t];
}

__global__ __launch_bounds__(SCAN_B) void scan2_k(int* __restrict__ bsum, int nb) {
    __shared__ int sh[SCAN_B];
    int t = threadIdx.x;
    int v = (t < nb) ? bsum[t] : 0;
    sh[t] = v;
    __syncthreads();
    for (int off = 1; off < SCAN_B; off <<= 1) {
        int x = (t >= off) ? sh[t - off] : 0;
        __syncthreads();
        sh[t] += x;
        __syncthreads();
    }
    if (t < nb) bsum[t] = sh[t] - v;
}

__global__ __launch_bounds__(SCAN_B) void scan3_k(int* __restrict__ excl,
                                                  const int* __restrict__ bsum,
                                                  int n, int e) {
    int i = blockIdx.x * SCAN_B + threadIdx.x;
    if (i < n) excl[i] += bsum[blockIdx.x];
    if (i == 0) excl[n] = e;
}

// ---------- fill CSR buckets: eidx sorted by dst, values = src ----------
__global__ void bucket_k(const int* __restrict__ src, const int* __restrict__ dst,
                         const int* __restrict__ rowptr, int* __restrict__ fill,
                         int* __restrict__ eidx, int e) {
    int i = blockIdx.x * blockDim.x + threadIdx.x;
    if (i >= e) return;
    int d = dst[i];
    int pos = rowptr[d] + atomicAdd(&fill[d], 1);
    eidx[pos] = src[i];
}

// ---------- gather for F=4 (scalar, 4 lanes/node): B[d] = A[d] + sum A[src] ----------
__global__ __launch_bounds__(256) void gatherX_k(const int* __restrict__ rowptr,
                                                 const int* __restrict__ eidx,
                                                 const float* __restrict__ A,
                                                 float* __restrict__ B, int n) {
    int t = threadIdx.x;
    int node = blockIdx.x * 64 + (t >> 2);
    int f = t & 3;
    if (node >= n) return;
    int e0 = rowptr[node], e1 = rowptr[node + 1];
    float acc = A[(size_t)node * 4 + f];
    int e = e0;
    for (; e + 4 <= e1; e += 4) {
        int s0 = eidx[e], s1 = eidx[e + 1], s2 = eidx[e + 2], s3 = eidx[e + 3];
        float v0 = A[(size_t)s0 * 4 + f], v1 = A[(size_t)s1 * 4 + f];
        float v2 = A[(size_t)s2 * 4 + f], v3 = A[(size_t)s3 * 4 + f];
        acc += (v0 + v1) + (v2 + v3);
    }
    for (; e < e1; ++e) acc += A[(size_t)eidx[e] * 4 + f];
    B[(size_t)node * 4 + f] = acc;
}

// ---------- vectorized gather (float4, F/4 lanes per node) ----------
template <int F>
__global__ __launch_bounds__(256) void gather4_k(const int* __restrict__ rowptr,
                                                 const int* __restrict__ eidx,
                                                 const float* __restrict__ A,
                                                 float* __restrict__ B, int n) {
    constexpr int FV = F / 4;
    constexpr int NPB = 256 / FV;
    int t = threadIdx.x;
    int node = blockIdx.x * NPB + t / FV;
    int j = (t % FV) * 4;
    if (node >= n) return;
    int e0 = rowptr[node], e1 = rowptr[node + 1];
    const float* __restrict__ Aj = A + j;
    float4 acc = *(const float4*)(Aj + (size_t)node * F);
    int e = e0;
    for (; e + 4 <= e1; e += 4) {
        int s0 = eidx[e], s1 = eidx[e + 1], s2 = eidx[e + 2], s3 = eidx[e + 3];
        float4 v0 = *(const float4*)(Aj + (size_t)s0 * F);
        float4 v1 = *(const float4*)(Aj + (size_t)s1 * F);
        float4 v2 = *(const float4*)(Aj + (size_t)s2 * F);
        float4 v3 = *(const float4*)(Aj + (size_t)s3 * F);
        acc.x += (v0.x + v1.x) + (v2.x + v3.x);
        acc.y += (v0.y + v1.y) + (v2.y + v3.y);
        acc.z += (v0.z + v1.z) + (v2.z + v3.z);
        acc.w += (v0.w + v1.w) + (v2.w + v3.w);
    }
    for (; e < e1; ++e) {
        float4 v = *(const float4*)(Aj + (size_t)eidx[e] * F);
        acc.x += v.x; acc.y += v.y; acc.z += v.z; acc.w += v.w;
    }
    *(float4*)(B + (size_t)node * F + j) = acc;
}

// ---------- post-aggregation matmul ----------
// out[node][f] = relu(dinv[node] * (g[node,:FinR] . W[:,f]) + bias[f]) [* dinv if SCALE_OUT]
template <int FinS, int FinR, int Fout, int NB, bool SCALE_OUT>  // NB*Fout == 256
__global__ __launch_bounds__(256) void mmA_k(
    const float* __restrict__ G, const float* __restrict__ W,
    const float* __restrict__ bias, const float* __restrict__ dinv,
    float* __restrict__ Aout, int n) {
    __shared__ float act[NB * FinS];
    int t = threadIdx.x;
    int node0 = blockIdx.x * NB;
    for (int i = t; i < NB * FinS; i += 256) {
        int nl = i / FinS;
        int node = node0 + nl;
        act[i] = (node < n) ? G[(size_t)node * FinS + (i - nl * FinS)] : 0.0f;
    }
    __syncthreads();
    int nl = t / Fout, f = t - nl * Fout;
    int node = node0 + nl;
    if (node < n) {
        float acc = 0.0f;
#pragma unroll
        for (int k = 0; k < FinR; ++k)
            acc = fmaf(act[nl * FinS + k], W[k * Fout + f], acc);
        float s = dinv[node];
        float v = fmaxf(fmaf(s, acc, bias[f]), 0.0f);
        Aout[(size_t)node * Fout + f] = SCALE_OUT ? v * s : v;
    }
}

// ---------- segmented mean-pool over pre-activated h3 (batch sorted) ----------
#define NPB_POOL 32
__global__ __launch_bounds__(128) void pool2_k(
    const float* __restrict__ H, const int* __restrict__ batch,
    float* __restrict__ pooled, float* __restrict__ cntg, int n) {
    int f = threadIdx.x;
    int n0 = blockIdx.x * NPB_POOL;
    if (n0 >= n) return;
    int n1 = min(n0 + NPB_POOL, n);
    float acc = 0.0f, cct = 0.0f;
    int cur = batch[n0];
    for (int node = n0; node < n1; ++node) {
        int g = batch[node];
        if (g != cur) {
            atomicAdd(&pooled[cur * 128 + f], acc);
            if (f == 0) atomicAdd(&cntg[cur], cct);
            acc = 0.0f;
            cct = 0.0f;
            cur = g;
        }
        acc += H[(size_t)node * 128 + f];
        cct += 1.0f;
    }
    atomicAdd(&pooled[cur * 128 + f], acc);
    if (f == 0) atomicAdd(&cntg[cur], cct);
}

// ---------- head: out[g,:] = relu(mean_pool @ Wf1 + bf1) @ Wf2 + bf2 ----------
__global__ __launch_bounds__(64) void head_k(
    const float* __restrict__ pooled, const float* __restrict__ cnt,
    const float* __restrict__ Wf1, const float* __restrict__ bf1,
    const float* __restrict__ Wf2, const float* __restrict__ bf2,
    float* __restrict__ out) {
    __shared__ float pm[128];
    __shared__ float z[32];
    int g = blockIdx.x, t = threadIdx.x;
    float c = fmaxf(cnt[g], 1.0f);
    pm[t] = pooled[g * 128 + t] / c;
    pm[t + 64] = pooled[g * 128 + 64 + t] / c;
    __syncthreads();
    if (t < 32) {
        float acc = bf1[t];
#pragma unroll 4
        for (int k = 0; k < 128; ++k) acc = fmaf(pm[k], Wf1[k * 32 + t], acc);
        z[t] = fmaxf(acc, 0.0f);
    }
    __syncthreads();
    if (t < 4) {
        float acc = bf2[t];
#pragma unroll
        for (int j = 0; j < 32; ++j) acc = fmaf(z[j], Wf2[j * 4 + t], acc);
        out[g * 4 + t] = acc;
    }
}

extern "C" void kernel_launch(void* const* d_in, const int* in_sizes, int n_in,
                              void* d_out, int out_size, void* d_ws, size_t ws_size,
                              hipStream_t stream) {
    const float* x    = (const float*)d_in[0];
    const int*   ei   = (const int*)d_in[1];
    const int*   batch= (const int*)d_in[2];
    const float* W1   = (const float*)d_in[3];
    const float* b1   = (const float*)d_in[4];
    const float* W2   = (const float*)d_in[5];
    const float* b2   = (const float*)d_in[6];
    const float* W3   = (const float*)d_in[7];
    const float* b3   = (const float*)d_in[8];
    const float* Wf1  = (const float*)d_in[9];
    const float* bf1  = (const float*)d_in[10];
    const float* Wf2  = (const float*)d_in[11];
    const float* bf2  = (const float*)d_in[12];
    float* out = (float*)d_out;

    // workspace layout (4-byte elems); P reused for xs/A2/A3/h3, G for g1/g2/g3
    float* P      = (float*)d_ws;              // N*128
    float* G      = P + (size_t)NN * 128;      // N*64
    float* dinv   = G + (size_t)NN * 64;       // N
    float* pooled = dinv + NN;                 // NG*128  } one memset
    float* cntg   = pooled + NG * 128;         // NG      }
    int* cnt      = (int*)(cntg + NG);         // N       }
    int* fill     = cnt + NN;                  // N       }
    int* rowptr   = fill + NN;                 // N+1
    int* bsum     = rowptr + NN + 1;           // 256
    int* eidx     = bsum + 256;                // E

    const int* src = ei;
    const int* dst = ei + NE;

    const int NB_SCAN = (NN + SCAN_B - 1) / SCAN_B;  // 196

    // ---- CSR build (dst-sorted) + norms + x pre-scale ----
    hipMemsetAsync(pooled, 0, (size_t)(NG * 128 + NG + 2 * NN) * 4, stream);
    hist_k<<<(NE + 255) / 256, 256, 0, stream>>>(dst, cnt, NE);
    dinvxs_k<<<(NN + 255) / 256, 256, 0, stream>>>(cnt, x, dinv, P, NN);
    scan1_k<<<NB_SCAN, SCAN_B, 0, stream>>>(cnt, rowptr, bsum, NN);
    scan2_k<<<1, SCAN_B, 0, stream>>>(bsum, NB_SCAN);
    scan3_k<<<NB_SCAN, SCAN_B, 0, stream>>>(rowptr, bsum, NN, NE);
    bucket_k<<<(NE + 255) / 256, 256, 0, stream>>>(src, dst, rowptr, fill, eidx, NE);

    // ---- layer 1: gather x (4-wide), then 3->32 matmul ----
    gatherX_k<<<(NN + 63) / 64, 256, 0, stream>>>(rowptr, eidx, P, G, NN);
    mmA_k<4, 3, 32, 8, true><<<(NN + 7) / 8, 256, 0, stream>>>(G, W1, b1, dinv, P, NN);

    // ---- layer 2: gather 32-wide, then 32->64 matmul ----
    gather4_k<32><<<(NN + 31) / 32, 256, 0, stream>>>(rowptr, eidx, P, G, NN);
    mmA_k<32, 32, 64, 4, true><<<(NN + 3) / 4, 256, 0, stream>>>(G, W2, b2, dinv, P, NN);

    // ---- layer 3: gather 64-wide, then 64->128 matmul (no out-scale; h3 pre-activated) ----
    gather4_k<64><<<(NN + 15) / 16, 256, 0, stream>>>(rowptr, eidx, P, G, NN);
    mmA_k<64, 64, 128, 2, false><<<(NN + 1) / 2, 256, 0, stream>>>(G, W3, b3, dinv, P, NN);

    // ---- pool + head ----
    pool2_k<<<(NN + NPB_POOL - 1) / NPB_POOL, 128, 0, stream>>>(P, batch, pooled, cntg, NN);
    head_k<<<NG, 64, 0, stream>>>(pooled, cntg, Wf1, bf1, Wf2, bf2, out);
}

// Round 4
// 285.615 us; speedup vs baseline: 9.2492x; 1.1276x over previous
//
#include <hip/hip_runtime.h>

#define NN 50000
#define NE 800000
#define NG 512

// ---------- histogram of dst (in-degree) ----------
__global__ void hist_k(const int* __restrict__ dst, int* __restrict__ cnt, int e) {
    int i = blockIdx.x * blockDim.x + threadIdx.x;
    if (i < e) atomicAdd(&cnt[dst[i]], 1);
}

// ---------- dinv = rsqrt(deg), xs[n,4] = dinv[n]*x[n,0:3] (padded) ----------
__global__ void dinvxs_k(const int* __restrict__ cnt, const float* __restrict__ x,
                         float* __restrict__ dinv, float* __restrict__ xs, int n) {
    int i = blockIdx.x * blockDim.x + threadIdx.x;
    if (i >= n) return;
    float d = rsqrtf((float)(cnt[i] + 1));  // +1 self-loop
    dinv[i] = d;
    float4 v;
    v.x = x[i * 3 + 0] * d;
    v.y = x[i * 3 + 1] * d;
    v.z = x[i * 3 + 2] * d;
    v.w = 0.0f;
    *(float4*)(xs + (size_t)i * 4) = v;
}

// ---------- 3-kernel exclusive prefix scan over cnt -> rowptr ----------
#define SCAN_B 256
__global__ __launch_bounds__(SCAN_B) void scan1_k(const int* __restrict__ cnt,
                                                  int* __restrict__ excl,
                                                  int* __restrict__ bsum, int n) {
    __shared__ int sh[SCAN_B];
    int t = threadIdx.x, i = blockIdx.x * SCAN_B + t;
    int v = (i < n) ? cnt[i] : 0;
    sh[t] = v;
    __syncthreads();
    for (int off = 1; off < SCAN_B; off <<= 1) {
        int x = (t >= off) ? sh[t - off] : 0;
        __syncthreads();
        sh[t] += x;
        __syncthreads();
    }
    if (i < n) excl[i] = sh[t] - v;
    if (t == SCAN_B - 1) bsum[blockIdx.x] = sh[t];
}

__global__ __launch_bounds__(SCAN_B) void scan2_k(int* __restrict__ bsum, int nb) {
    __shared__ int sh[SCAN_B];
    int t = threadIdx.x;
    int v = (t < nb) ? bsum[t] : 0;
    sh[t] = v;
    __syncthreads();
    for (int off = 1; off < SCAN_B; off <<= 1) {
        int x = (t >= off) ? sh[t - off] : 0;
        __syncthreads();
        sh[t] += x;
        __syncthreads();
    }
    if (t < nb) bsum[t] = sh[t] - v;
}

__global__ __launch_bounds__(SCAN_B) void scan3_k(int* __restrict__ excl,
                                                  const int* __restrict__ bsum,
                                                  int n, int e) {
    int i = blockIdx.x * SCAN_B + threadIdx.x;
    if (i < n) excl[i] += bsum[blockIdx.x];
    if (i == 0) excl[n] = e;
}

// ---------- fill CSR buckets: eidx sorted by dst, values = src ----------
__global__ void bucket_k(const int* __restrict__ src, const int* __restrict__ dst,
                         const int* __restrict__ rowptr, int* __restrict__ fill,
                         int* __restrict__ eidx, int e) {
    int i = blockIdx.x * blockDim.x + threadIdx.x;
    if (i >= e) return;
    int d = dst[i];
    int pos = rowptr[d] + atomicAdd(&fill[d], 1);
    eidx[pos] = src[i];
}

// ---------- gather for F=4 (scalar, 4 lanes/node): B[d] = A[d] + sum A[src] ----------
__global__ __launch_bounds__(256) void gatherX_k(const int* __restrict__ rowptr,
                                                 const int* __restrict__ eidx,
                                                 const float* __restrict__ A,
                                                 float* __restrict__ B, int n) {
    int t = threadIdx.x;
    int node = blockIdx.x * 64 + (t >> 2);
    int f = t & 3;
    if (node >= n) return;
    int e0 = rowptr[node], e1 = rowptr[node + 1];
    float acc = A[(size_t)node * 4 + f];
    int e = e0;
    for (; e + 4 <= e1; e += 4) {
        int s0 = eidx[e], s1 = eidx[e + 1], s2 = eidx[e + 2], s3 = eidx[e + 3];
        float v0 = A[(size_t)s0 * 4 + f], v1 = A[(size_t)s1 * 4 + f];
        float v2 = A[(size_t)s2 * 4 + f], v3 = A[(size_t)s3 * 4 + f];
        acc += (v0 + v1) + (v2 + v3);
    }
    for (; e < e1; ++e) acc += A[(size_t)eidx[e] * 4 + f];
    B[(size_t)node * 4 + f] = acc;
}

// ---------- vectorized gather (float4, F/4 lanes per node) ----------
template <int F>
__global__ __launch_bounds__(256) void gather4_k(const int* __restrict__ rowptr,
                                                 const int* __restrict__ eidx,
                                                 const float* __restrict__ A,
                                                 float* __restrict__ B, int n) {
    constexpr int FV = F / 4;
    constexpr int NPB = 256 / FV;
    int t = threadIdx.x;
    int node = blockIdx.x * NPB + t / FV;
    int j = (t % FV) * 4;
    if (node >= n) return;
    int e0 = rowptr[node], e1 = rowptr[node + 1];
    const float* __restrict__ Aj = A + j;
    float4 acc = *(const float4*)(Aj + (size_t)node * F);
    int e = e0;
    for (; e + 4 <= e1; e += 4) {
        int s0 = eidx[e], s1 = eidx[e + 1], s2 = eidx[e + 2], s3 = eidx[e + 3];
        float4 v0 = *(const float4*)(Aj + (size_t)s0 * F);
        float4 v1 = *(const float4*)(Aj + (size_t)s1 * F);
        float4 v2 = *(const float4*)(Aj + (size_t)s2 * F);
        float4 v3 = *(const float4*)(Aj + (size_t)s3 * F);
        acc.x += (v0.x + v1.x) + (v2.x + v3.x);
        acc.y += (v0.y + v1.y) + (v2.y + v3.y);
        acc.z += (v0.z + v1.z) + (v2.z + v3.z);
        acc.w += (v0.w + v1.w) + (v2.w + v3.w);
    }
    for (; e < e1; ++e) {
        float4 v = *(const float4*)(Aj + (size_t)eidx[e] * F);
        acc.x += v.x; acc.y += v.y; acc.z += v.z; acc.w += v.w;
    }
    *(float4*)(B + (size_t)node * F + j) = acc;
}

// ---------- layer-1 matmul (K=3, LDS-staged) ----------
// out[node][f] = relu(dinv*(g . W) + bias) * dinv
template <int FinS, int FinR, int Fout, int NB, bool SCALE_OUT>  // NB*Fout == 256
__global__ __launch_bounds__(256) void mmA_k(
    const float* __restrict__ G, const float* __restrict__ W,
    const float* __restrict__ bias, const float* __restrict__ dinv,
    float* __restrict__ Aout, int n) {
    __shared__ float act[NB * FinS];
    int t = threadIdx.x;
    int node0 = blockIdx.x * NB;
    for (int i = t; i < NB * FinS; i += 256) {
        int nl = i / FinS;
        int node = node0 + nl;
        act[i] = (node < n) ? G[(size_t)node * FinS + (i - nl * FinS)] : 0.0f;
    }
    __syncthreads();
    int nl = t / Fout, f = t - nl * Fout;
    int node = node0 + nl;
    if (node < n) {
        float acc = 0.0f;
#pragma unroll
        for (int k = 0; k < FinR; ++k)
            acc = fmaf(act[nl * FinS + k], W[k * Fout + f], acc);
        float s = dinv[node];
        float v = fmaxf(fmaf(s, acc, bias[f]), 0.0f);
        Aout[(size_t)node * Fout + f] = SCALE_OUT ? v * s : v;
    }
}

// ---------- register-tiled matmul: NPT nodes x 4 f per thread ----------
// out[node][f] = relu(dinv*(g . W) + bias) [* dinv if SCALE_OUT]
template <int Fin, int Fout, int NPB, bool SCALE_OUT>
__global__ __launch_bounds__(256) void mmB_k(
    const float* __restrict__ G, const float* __restrict__ W,
    const float* __restrict__ bias, const float* __restrict__ dinv,
    float* __restrict__ Aout, int n) {
    constexpr int FL = Fout / 4;        // f-lanes
    constexpr int NGRP = 256 / FL;      // node groups per block
    constexpr int NPT = NPB / NGRP;     // nodes per thread
    __shared__ float act[NPB][Fin];
    int t = threadIdx.x;
    int node0 = blockIdx.x * NPB;
    // stage act rows (coalesced float4)
    constexpr int TOT4 = NPB * Fin / 4;
    const float4* __restrict__ G4 = (const float4*)(G + (size_t)node0 * Fin);
    float4* act4 = (float4*)&act[0][0];
    for (int i = t; i < TOT4; i += 256) {
        int nl = i / (Fin / 4);
        float4 v = make_float4(0.f, 0.f, 0.f, 0.f);
        if (node0 + nl < n) v = G4[i];
        act4[i] = v;
    }
    __syncthreads();
    int f4 = (t % FL) * 4;
    int nlbase = (t / FL) * NPT;
    float4 acc[NPT];
#pragma unroll
    for (int i = 0; i < NPT; ++i) acc[i] = make_float4(0.f, 0.f, 0.f, 0.f);
    for (int k = 0; k < Fin; k += 4) {
        float4 a[NPT];
#pragma unroll
        for (int i = 0; i < NPT; ++i) a[i] = *(const float4*)&act[nlbase + i][k];
#pragma unroll
        for (int kk = 0; kk < 4; ++kk) {
            float4 w = *(const float4*)(W + (size_t)(k + kk) * Fout + f4);
#pragma unroll
            for (int i = 0; i < NPT; ++i) {
                float av = (&a[i].x)[kk];
                acc[i].x = fmaf(av, w.x, acc[i].x);
                acc[i].y = fmaf(av, w.y, acc[i].y);
                acc[i].z = fmaf(av, w.z, acc[i].z);
                acc[i].w = fmaf(av, w.w, acc[i].w);
            }
        }
    }
    float4 bv = *(const float4*)(bias + f4);
#pragma unroll
    for (int i = 0; i < NPT; ++i) {
        int node = node0 + nlbase + i;
        if (node < n) {
            float s = dinv[node];
            float4 o;
            o.x = fmaxf(fmaf(s, acc[i].x, bv.x), 0.0f);
            o.y = fmaxf(fmaf(s, acc[i].y, bv.y), 0.0f);
            o.z = fmaxf(fmaf(s, acc[i].z, bv.z), 0.0f);
            o.w = fmaxf(fmaf(s, acc[i].w, bv.w), 0.0f);
            if (SCALE_OUT) { o.x *= s; o.y *= s; o.z *= s; o.w *= s; }
            *(float4*)(Aout + (size_t)node * Fout + f4) = o;
        }
    }
}

// ---------- segmented mean-pool over pre-activated h3 (batch sorted) ----------
#define NPB_POOL 32
__global__ __launch_bounds__(128) void pool2_k(
    const float* __restrict__ H, const int* __restrict__ batch,
    float* __restrict__ pooled, float* __restrict__ cntg, int n) {
    int f = threadIdx.x;
    int n0 = blockIdx.x * NPB_POOL;
    if (n0 >= n) return;
    int n1 = min(n0 + NPB_POOL, n);
    float acc = 0.0f, cct = 0.0f;
    int cur = batch[n0];
    for (int node = n0; node < n1; ++node) {
        int g = batch[node];
        if (g != cur) {
            atomicAdd(&pooled[cur * 128 + f], acc);
            if (f == 0) atomicAdd(&cntg[cur], cct);
            acc = 0.0f;
            cct = 0.0f;
            cur = g;
        }
        acc += H[(size_t)node * 128 + f];
        cct += 1.0f;
    }
    atomicAdd(&pooled[cur * 128 + f], acc);
    if (f == 0) atomicAdd(&cntg[cur], cct);
}

// ---------- head: out[g,:] = relu(mean_pool @ Wf1 + bf1) @ Wf2 + bf2 ----------
__global__ __launch_bounds__(64) void head_k(
    const float* __restrict__ pooled, const float* __restrict__ cnt,
    const float* __restrict__ Wf1, const float* __restrict__ bf1,
    const float* __restrict__ Wf2, const float* __restrict__ bf2,
    float* __restrict__ out) {
    __shared__ float pm[128];
    __shared__ float z[32];
    int g = blockIdx.x, t = threadIdx.x;
    float c = fmaxf(cnt[g], 1.0f);
    pm[t] = pooled[g * 128 + t] / c;
    pm[t + 64] = pooled[g * 128 + 64 + t] / c;
    __syncthreads();
    if (t < 32) {
        float acc = bf1[t];
#pragma unroll 4
        for (int k = 0; k < 128; ++k) acc = fmaf(pm[k], Wf1[k * 32 + t], acc);
        z[t] = fmaxf(acc, 0.0f);
    }
    __syncthreads();
    if (t < 4) {
        float acc = bf2[t];
#pragma unroll
        for (int j = 0; j < 32; ++j) acc = fmaf(z[j], Wf2[j * 4 + t], acc);
        out[g * 4 + t] = acc;
    }
}

extern "C" void kernel_launch(void* const* d_in, const int* in_sizes, int n_in,
                              void* d_out, int out_size, void* d_ws, size_t ws_size,
                              hipStream_t stream) {
    const float* x    = (const float*)d_in[0];
    const int*   ei   = (const int*)d_in[1];
    const int*   batch= (const int*)d_in[2];
    const float* W1   = (const float*)d_in[3];
    const float* b1   = (const float*)d_in[4];
    const float* W2   = (const float*)d_in[5];
    const float* b2   = (const float*)d_in[6];
    const float* W3   = (const float*)d_in[7];
    const float* b3   = (const float*)d_in[8];
    const float* Wf1  = (const float*)d_in[9];
    const float* bf1  = (const float*)d_in[10];
    const float* Wf2  = (const float*)d_in[11];
    const float* bf2  = (const float*)d_in[12];
    float* out = (float*)d_out;

    // workspace layout (4-byte elems); P reused for xs/A2/A3/h3, G for g1/g2/g3
    float* P      = (float*)d_ws;              // N*128
    float* G      = P + (size_t)NN * 128;      // N*64
    float* dinv   = G + (size_t)NN * 64;       // N
    float* pooled = dinv + NN;                 // NG*128  } one memset
    float* cntg   = pooled + NG * 128;         // NG      }
    int* cnt      = (int*)(cntg + NG);         // N       }
    int* fill     = cnt + NN;                  // N       }
    int* rowptr   = fill + NN;                 // N+1
    int* bsum     = rowptr + NN + 1;           // 256
    int* eidx     = bsum + 256;                // E

    const int* src = ei;
    const int* dst = ei + NE;

    const int NB_SCAN = (NN + SCAN_B - 1) / SCAN_B;  // 196

    // ---- CSR build (dst-sorted) + norms + x pre-scale ----
    hipMemsetAsync(pooled, 0, (size_t)(NG * 128 + NG + 2 * NN) * 4, stream);
    hist_k<<<(NE + 255) / 256, 256, 0, stream>>>(dst, cnt, NE);
    dinvxs_k<<<(NN + 255) / 256, 256, 0, stream>>>(cnt, x, dinv, P, NN);
    scan1_k<<<NB_SCAN, SCAN_B, 0, stream>>>(cnt, rowptr, bsum, NN);
    scan2_k<<<1, SCAN_B, 0, stream>>>(bsum, NB_SCAN);
    scan3_k<<<NB_SCAN, SCAN_B, 0, stream>>>(rowptr, bsum, NN, NE);
    bucket_k<<<(NE + 255) / 256, 256, 0, stream>>>(src, dst, rowptr, fill, eidx, NE);

    // ---- layer 1: gather x (4-wide), then 3->32 matmul ----
    gatherX_k<<<(NN + 63) / 64, 256, 0, stream>>>(rowptr, eidx, P, G, NN);
    mmA_k<4, 3, 32, 8, true><<<(NN + 7) / 8, 256, 0, stream>>>(G, W1, b1, dinv, P, NN);

    // ---- layer 2: gather 32-wide, then 32->64 register-tiled matmul ----
    gather4_k<32><<<(NN + 31) / 32, 256, 0, stream>>>(rowptr, eidx, P, G, NN);
    mmB_k<32, 64, 32, true><<<(NN + 31) / 32, 256, 0, stream>>>(G, W2, b2, dinv, P, NN);

    // ---- layer 3: gather 64-wide, then 64->128 register-tiled matmul ----
    gather4_k<64><<<(NN + 15) / 16, 256, 0, stream>>>(rowptr, eidx, P, G, NN);
    mmB_k<64, 128, 32, false><<<(NN + 31) / 32, 256, 0, stream>>>(G, W3, b3, dinv, P, NN);

    // ---- pool + head ----
    pool2_k<<<(NN + NPB_POOL - 1) / NPB_POOL, 128, 0, stream>>>(P, batch, pooled, cntg, NN);
    head_k<<<NG, 64, 0, stream>>>(pooled, cntg, Wf1, bf1, Wf2, bf2, out);
}